// Round 10
// baseline (189.853 us; speedup 1.0000x reference)
//
#include <hip/hip_runtime.h>
#include <math.h>

#define NB 8192      // batch rows
#define NC 1000      // classes
#define NF4 250      // NC / 4 float4s per row

// ws layout (floats, stride NB):
//  [0..4] margin | [5..9] gathered | [10..14] KD | [15] CE
//  [16] row min of gathered (4 teachers) | [17] row max of row-maxes

#define LOG2E 1.4426950408889634f
#define LN2   0.6931471805599453f
#define K20C  (LOG2E / 20.0f)

__device__ __forceinline__ float fexp2(float x) { return __builtin_amdgcn_exp2f(x); }
__device__ __forceinline__ float flog2(float x) { return __builtin_amdgcn_logf(x); }

// Counted waits; two-level stringify so macro args expand to literals.
#define VMWAIT_(N)                                       \
  asm volatile("s_waitcnt vmcnt(" #N ")" ::: "memory");  \
  __builtin_amdgcn_sched_barrier(0)
#define VMWAIT(N) VMWAIT_(N)
#define LGKM0                                            \
  asm volatile("s_waitcnt lgkmcnt(0)" ::: "memory");     \
  __builtin_amdgcn_sched_barrier(0)

// Direct global->LDS (zero VGPR payload, cannot be sunk/spilled).
typedef const __attribute__((address_space(1))) unsigned int gu32;
typedef __attribute__((address_space(3))) unsigned int lu32;
__device__ __forceinline__ void stage16(const void* g, void* l) {
  __builtin_amdgcn_global_load_lds((gu32*)g, (lu32*)l, 16, 0, 0);
}

// ---------------- DPP wave reductions (VALU pipe) ----------------
template <int CTRL>
__device__ __forceinline__ float dpp_mov(float v, float ident) {
  return __uint_as_float((unsigned)__builtin_amdgcn_update_dpp(
      (int)__float_as_uint(ident), (int)__float_as_uint(v), CTRL, 0xF, 0xF,
      false));
}

__device__ __forceinline__ float dppredsum(float v) {
  v += dpp_mov<0x111>(v, 0.f);
  v += dpp_mov<0x112>(v, 0.f);
  v += dpp_mov<0x114>(v, 0.f);
  v += dpp_mov<0x118>(v, 0.f);
  v += dpp_mov<0x142>(v, 0.f);
  v += dpp_mov<0x143>(v, 0.f);
  return v;  // lane 63 = full sum
}

__device__ __forceinline__ void dppredtop2(float& t1, float& t2) {
  const float NI = -INFINITY;
#define T2STEP(C)                                   \
  {                                                 \
    float i1 = dpp_mov<C>(t1, NI);                  \
    float i2 = dpp_mov<C>(t2, NI);                  \
    t2 = fmaxf(fmaxf(t2, i2), fminf(t1, i1));       \
    t1 = fmaxf(t1, i1);                             \
  }
  T2STEP(0x111) T2STEP(0x112) T2STEP(0x114) T2STEP(0x118)
  T2STEP(0x142) T2STEP(0x143)
#undef T2STEP
}

// shfl butterfly helpers (k_final): result lands in ALL lanes
__device__ __forceinline__ float wredsum(float v) {
#pragma unroll
  for (int m = 32; m >= 1; m >>= 1) v += __shfl_xor(v, m, 64);
  return v;
}
__device__ __forceinline__ float wredmax(float v) {
#pragma unroll
  for (int m = 32; m >= 1; m >>= 1) v = fmaxf(v, __shfl_xor(v, m, 64));
  return v;
}
__device__ __forceinline__ float wredmin(float v) {
#pragma unroll
  for (int m = 32; m >= 1; m >>= 1) v = fminf(v, __shfl_xor(v, m, 64));
  return v;
}
__device__ __forceinline__ float f4get(const float4& v, int e) {
  return e == 0 ? v.x : e == 1 ? v.y : e == 2 ? v.z : v.w;
}
__device__ __forceinline__ float& f4ref(float4& v, int e) {
  return e == 0 ? v.x : e == 1 ? v.y : e == 2 ? v.z : v.w;
}

// Per-matrix accumulate (bit-identical op order to verified R9 version)
__device__ __forceinline__ void proc_mat(const float4& c, const float4& cs,
                                         float& t1, float& t2, float& Zm,
                                         float& S1m, float4& sum4) {
#pragma unroll
  for (int e = 0; e < 4; ++e) {
    float w = f4get(c, e);
    float wsv = f4get(cs, e);
    t2 = fmaxf(t2, fminf(t1, w));
    t1 = fmaxf(t1, w);
    float et = fexp2(w * K20C);
    Zm += et;
    S1m = fmaf(et, w - wsv, S1m);
    f4ref(sum4, e) += w;
  }
}

// PERSISTENT 4-ROW WAVES (R10). R0-R9 ledger: every one-row-per-wave clean
// schedule = 65-77 µs; per row ~4900cy wall vs ~500cy VMEM + ~510cy VALU
// work; the waste is the per-row cold start (~900cy, empty queue) + tail
// (reduction/epilogue with drained queue, ~600-1000cy), and achieved
// residency pins at ~10 waves/CU no matter what LDS/VGPR permit. Fix: each
// wave processes 4 rows with a seamless 16-slot pipeline (ping-pong 5 KB
// buffers): cold start paid once per 4 rows, and the vmem queue stays
// NON-EMPTY through the reductions (next row's chunks + gathers in flight).
// Exact vmcnt ledger below counts stages(5)/gathers(5)/epilogue stores(18);
// gathers issue 3 slots before use; targets preloaded via one vector load.
// Needs only 2 blocks/CU (8 waves) -> immune to the occupancy cap.
__global__ __launch_bounds__(256, 4) void k_rowstats(
    const float* __restrict__ o1, const float* __restrict__ o2,
    const float* __restrict__ o3, const float* __restrict__ o4,
    const float* __restrict__ os, const int* __restrict__ tg,
    float* __restrict__ ws, float* __restrict__ out) {
  const int lane = threadIdx.x & 63;
  const int wv = threadIdx.x >> 6;                 // 0..3
  const int rowbase = (blockIdx.x * 4 + wv) * 4;   // 4 rows per wave
  __shared__ float4 lds[4][2][5][64];              // [wave][buf][mat][lane] 40KB

  if (blockIdx.x == 0 && threadIdx.x == 0) out[0] = 0.0f;

  // one vector load covers this wave's 4 targets (vmcnt op; drained @slot0)
  int tgv = tg[rowbase + (lane & 3)];

#define STAGES(s)                                                         \
  do {                                                                    \
    const int r_ = (s) >> 2, c_ = (s) & 3;                                \
    const size_t b_ = (size_t)(rowbase + r_) * NC;                        \
    int f_ = lane + (c_ << 6);                                            \
    if (f_ > NF4 - 1) f_ = NF4 - 1; /* clamp: dup load, masked below */   \
    stage16((const float4*)(o1 + b_) + f_, &lds[wv][(s) & 1][0][0]);      \
    stage16((const float4*)(o2 + b_) + f_, &lds[wv][(s) & 1][1][0]);      \
    stage16((const float4*)(o3 + b_) + f_, &lds[wv][(s) & 1][2][0]);      \
    stage16((const float4*)(o4 + b_) + f_, &lds[wv][(s) & 1][3][0]);      \
    stage16((const float4*)(os + b_) + f_, &lds[wv][(s) & 1][4][0]);      \
  } while (0)

#define GATHER(r)                                                         \
  do {                                                                    \
    const int tgt_ = __shfl(tgv, (r), 64);                                \
    const size_t gb_ = (size_t)(rowbase + (r)) * NC + tgt_;               \
    g1 = o1[gb_]; g2 = o2[gb_]; g3 = o3[gb_]; g4 = o4[gb_]; g5 = os[gb_]; \
  } while (0)

  STAGES(0);
  STAGES(1);
  // queue: [tgv(1)][S0(5)][S1(5)]

  float t1[5], t2[5], Z[5], S1[5], Z1, Z20;
  float g1, g2, g3, g4, g5;
#define RESETACC                                                          \
  do {                                                                    \
    _Pragma("unroll") for (int t = 0; t < 5; ++t) {                       \
      t1[t] = -INFINITY; t2[t] = -INFINITY; Z[t] = 0.f; S1[t] = 0.f;      \
    }                                                                     \
    Z1 = 0.f; Z20 = 0.f;                                                  \
  } while (0)
  RESETACC;

  // Row-end: DPP reduce, lane-63 epilogue (18 stores -> counted in ledger),
  // accumulator reset. Math identical to the verified R9 epilogue.
#define REDUCE_EPI(r)                                                     \
  do {                                                                    \
    _Pragma("unroll") for (int t = 0; t < 5; ++t) dppredtop2(t1[t], t2[t]); \
    _Pragma("unroll") for (int t = 0; t < 5; ++t) {                       \
      Z[t] = dppredsum(Z[t]); S1[t] = dppredsum(S1[t]);                   \
    }                                                                     \
    Z1 = dppredsum(Z1);                                                   \
    Z20 = dppredsum(Z20);                                                 \
    if (lane == 63) {                                                     \
      const int row_ = rowbase + (r);                                     \
      const float gm_ = ((g1 + g2) + g3 + g4) * 0.25f;                    \
      float gg_[5] = {g1, g2, g3, g4, gm_};                               \
      const float lse_s_ = flog2(Z20) * LN2;                              \
      const float CE_ = flog2(Z1) * LN2 - g5;                             \
      _Pragma("unroll") for (int t = 0; t < 5; ++t) {                     \
        float lse_t_ = flog2(Z[t]) * LN2;                                 \
        float KD_ = 400.0f * (S1[t] / (20.0f * Z[t]) - lse_t_ + lse_s_);  \
        float mg_ = (t1[t] == gg_[t]) ? (t1[t] - t2[t]) : 0.0f;           \
        ws[(size_t)t * NB + row_] = mg_;                                  \
        ws[(size_t)(5 + t) * NB + row_] = gg_[t];                         \
        ws[(size_t)(10 + t) * NB + row_] = KD_;                           \
      }                                                                   \
      ws[(size_t)15 * NB + row_] = CE_;                                   \
      ws[(size_t)16 * NB + row_] = fminf(fminf(g1, g2), fminf(g3, g4));   \
      ws[(size_t)17 * NB + row_] =                                        \
          fmaxf(fmaxf(t1[0], t1[1]), fmaxf(t1[2], t1[3]));                \
    }                                                                     \
    RESETACC;                                                             \
  } while (0)

  // One pipeline slot. Order: wait -> ds_read -> lgkm -> stage -> gather ->
  // mimic tail -> (row end). proc_mat/e-order identical to R9.
#define SLOT(WAITN, BUF, ACT, STAGE_STMT, GATHER_STMT, ROWEND_STMT)       \
  do {                                                                    \
    VMWAIT(WAITN);                                                        \
    float4 rs_ = lds[wv][BUF][4][lane];                                   \
    float4 sum4_ = {0.f, 0.f, 0.f, 0.f};                                  \
    float4 cm_;                                                           \
    cm_ = lds[wv][BUF][0][lane];                                          \
    if (ACT) proc_mat(cm_, rs_, t1[0], t2[0], Z[0], S1[0], sum4_);        \
    cm_ = lds[wv][BUF][1][lane];                                          \
    if (ACT) proc_mat(cm_, rs_, t1[1], t2[1], Z[1], S1[1], sum4_);        \
    cm_ = lds[wv][BUF][2][lane];                                          \
    if (ACT) proc_mat(cm_, rs_, t1[2], t2[2], Z[2], S1[2], sum4_);        \
    cm_ = lds[wv][BUF][3][lane];                                          \
    if (ACT) proc_mat(cm_, rs_, t1[3], t2[3], Z[3], S1[3], sum4_);        \
    LGKM0; /* ds_reads retired -> buffer safe to overwrite */             \
    STAGE_STMT;                                                           \
    GATHER_STMT;                                                          \
    if (ACT) {                                                            \
      _Pragma("unroll") for (int e = 0; e < 4; ++e) {                     \
        float wsv = f4get(rs_, e);                                        \
        float wm = f4get(sum4_, e) * 0.25f;                               \
        t2[4] = fmaxf(t2[4], fminf(t1[4], wm));                           \
        t1[4] = fmaxf(t1[4], wm);                                         \
        float et = fexp2(wm * K20C);                                      \
        Z[4] += et;                                                       \
        S1[4] = fmaf(et, wm - wsv, S1[4]);                                \
        Z1 += fexp2(wsv * LOG2E);                                         \
        Z20 += fexp2(wsv * K20C);                                         \
      }                                                                   \
    }                                                                     \
    ROWEND_STMT;                                                          \
  } while (0)

  // vmcnt ledger (after-S_s counts; G=5, W=18 stores, all in-order):
  // s0:5  s1:10 s2:10 s3:5 | s4:23 s5:28 s6:10 s7:5 |
  // s8:23 s9:28 s10:10 s11:5 | s12:23 s13:28 s14:10 s15:0
  SLOT(5,  0, true,      STAGES(2),  GATHER(0), );               // s0  r0c0
  SLOT(10, 1, true,      STAGES(3),  ,          );               // s1  r0c1
  SLOT(10, 0, true,      STAGES(4),  ,          );               // s2  r0c2
  SLOT(5,  1, lane < 58, STAGES(5),  ,          REDUCE_EPI(0));  // s3  r0c3
  SLOT(23, 0, true,      STAGES(6),  GATHER(1), );               // s4  r1c0
  SLOT(28, 1, true,      STAGES(7),  ,          );               // s5  r1c1
  SLOT(10, 0, true,      STAGES(8),  ,          );               // s6  r1c2
  SLOT(5,  1, lane < 58, STAGES(9),  ,          REDUCE_EPI(1));  // s7  r1c3
  SLOT(23, 0, true,      STAGES(10), GATHER(2), );               // s8  r2c0
  SLOT(28, 1, true,      STAGES(11), ,          );               // s9  r2c1
  SLOT(10, 0, true,      STAGES(12), ,          );               // s10 r2c2
  SLOT(5,  1, lane < 58, STAGES(13), ,          REDUCE_EPI(2));  // s11 r2c3
  SLOT(23, 0, true,      STAGES(14), GATHER(3), );               // s12 r3c0
  SLOT(28, 1, true,      STAGES(15), ,          );               // s13 r3c1
  SLOT(10, 0, true,      ,           ,          );               // s14 r3c2
  SLOT(0,  1, lane < 58, ,           ,          REDUCE_EPI(3));  // s15 r3c3

#undef STAGES
#undef GATHER
#undef RESETACC
#undef REDUCE_EPI
#undef SLOT
}

// Fused minmax + loss: 128 blocks x 1 wave (unchanged from R9).
__global__ __launch_bounds__(64) void k_final(const float* __restrict__ ws,
                                              float* __restrict__ out) {
  const int lane = threadIdx.x;

  float mn = INFINITY, mx = -INFINITY;
  const float4* mnp = (const float4*)(ws + (size_t)16 * NB);
  const float4* mxp = (const float4*)(ws + (size_t)17 * NB);
#pragma unroll
  for (int k = 0; k < 32; ++k) {
    int r4 = lane + (k << 6);
    float4 a = mnp[r4];
    float4 b = mxp[r4];
    mn = fminf(mn, fminf(fminf(a.x, a.y), fminf(a.z, a.w)));
    mx = fmaxf(mx, fmaxf(fmaxf(b.x, b.y), fmaxf(b.z, b.w)));
  }
  mn = wredmin(mn);
  mx = wredmax(mx);
  const float shift = (mn < 0.0f) ? (-mn + 1e-5f) : 0.0f;
  const float maxp = mx + shift;

  const int r = blockIdx.x * 64 + lane;
  const float K6 = LOG2E / 6.0f;

  float m[5], e[5];
#pragma unroll
  for (int t = 0; t < 5; ++t) m[t] = ws[(size_t)t * NB + r];
  float pm = fmaxf(fmaxf(fmaxf(m[0], m[1]), fmaxf(m[2], m[3])), m[4]);
  float Zl = 0.0f;
#pragma unroll
  for (int t = 0; t < 5; ++t) { e[t] = fexp2((m[t] - pm) * K6); Zl += e[t]; }
  float ce = ws[(size_t)15 * NB + r];
  float rl = 0.0f;
#pragma unroll
  for (int t = 0; t < 5; ++t) {
    float g = ws[(size_t)(5 + t) * NB + r];
    float kd = ws[(size_t)(10 + t) * NB + r];
    float w2 = (g + shift) / maxp;
    float loss = (1.0f - w2) * ce + w2 * kd;
    rl += e[t] * loss;
  }
  float acc = wredsum(rl / Zl);
  if (lane == 0) atomicAdd(out, acc * (1.0f / 8192.0f));
}

extern "C" void kernel_launch(void* const* d_in, const int* in_sizes, int n_in,
                              void* d_out, int out_size, void* d_ws, size_t ws_size,
                              hipStream_t stream) {
  const float* o1 = (const float*)d_in[0];
  const float* o2 = (const float*)d_in[1];
  const float* o3 = (const float*)d_in[2];
  const float* o4 = (const float*)d_in[3];
  const float* os = (const float*)d_in[4];
  const int* tg = (const int*)d_in[5];
  float* ws = (float*)d_ws;
  float* out = (float*)d_out;

  k_rowstats<<<NB / 16, 256, 0, stream>>>(o1, o2, o3, o4, os, tg, ws, out);
  k_final<<<NB / 64, 64, 0, stream>>>(ws, out);
}

// Round 11
// 185.930 us; speedup vs baseline: 1.0211x; 1.0211x over previous
//
#include <hip/hip_runtime.h>
#include <math.h>

#define NB 8192      // batch rows
#define NC 1000      // classes
#define NF4 250      // NC / 4 float4s per row

// ws layout (floats, stride NB):
//  [0..4]   margin per branch
//  [5..9]   gathered (raw) per branch
//  [10..14] KD per branch
//  [15]     CE
//  [16]     row min of gathered over 4 real teachers
//  [17]     row max of row-maxes over 4 real teachers

#define LOG2E 1.4426950408889634f
#define LN2   0.6931471805599453f

__device__ __forceinline__ float fexp2(float x) { return __builtin_amdgcn_exp2f(x); }
__device__ __forceinline__ float flog2(float x) { return __builtin_amdgcn_logf(x); }

// Explicit counted waits (T4). Each followed by sched_barrier(0) so hipcc
// cannot hoist dependent ops above the wait (guide rule 18).
#define VMWAIT(N)                                        \
  asm volatile("s_waitcnt vmcnt(" #N ")" ::: "memory");  \
  __builtin_amdgcn_sched_barrier(0)
#define LGKM0                                            \
  asm volatile("s_waitcnt lgkmcnt(0)" ::: "memory");     \
  __builtin_amdgcn_sched_barrier(0)

// Direct global->LDS (zero VGPR payload, cannot be sunk/spilled).
typedef const __attribute__((address_space(1))) unsigned int gu32;
typedef __attribute__((address_space(3))) unsigned int lu32;
__device__ __forceinline__ void stage16(const void* g, void* l) {
  __builtin_amdgcn_global_load_lds((gu32*)g, (lu32*)l, 16, 0, 0);
}

// ---------------- DPP wave reductions (VALU pipe, not DS) ----------------
template <int CTRL>
__device__ __forceinline__ float dpp_mov(float v, float ident) {
  return __uint_as_float((unsigned)__builtin_amdgcn_update_dpp(
      (int)__float_as_uint(ident), (int)__float_as_uint(v), CTRL, 0xF, 0xF,
      false));
}

__device__ __forceinline__ float dppredsum(float v) {
  v += dpp_mov<0x111>(v, 0.f);
  v += dpp_mov<0x112>(v, 0.f);
  v += dpp_mov<0x114>(v, 0.f);
  v += dpp_mov<0x118>(v, 0.f);
  v += dpp_mov<0x142>(v, 0.f);
  v += dpp_mov<0x143>(v, 0.f);
  return v;  // lane 63 = full sum
}

__device__ __forceinline__ void dppredtop2(float& t1, float& t2) {
  const float NI = -INFINITY;
#define T2STEP(C)                                   \
  {                                                 \
    float i1 = dpp_mov<C>(t1, NI);                  \
    float i2 = dpp_mov<C>(t2, NI);                  \
    t2 = fmaxf(fmaxf(t2, i2), fminf(t1, i1));       \
    t1 = fmaxf(t1, i1);                             \
  }
  T2STEP(0x111) T2STEP(0x112) T2STEP(0x114) T2STEP(0x118)
  T2STEP(0x142) T2STEP(0x143)
#undef T2STEP
  // lane 63 = (max, runner-up)
}

// shfl-based helpers (only used in the small finalize kernel)
__device__ __forceinline__ float wredsum(float v) {
#pragma unroll
  for (int m = 32; m >= 1; m >>= 1) v += __shfl_xor(v, m, 64);
  return v;
}
__device__ __forceinline__ float wredmax(float v) {
#pragma unroll
  for (int m = 32; m >= 1; m >>= 1) v = fmaxf(v, __shfl_xor(v, m, 64));
  return v;
}
__device__ __forceinline__ float wredmin(float v) {
#pragma unroll
  for (int m = 32; m >= 1; m >>= 1) v = fminf(v, __shfl_xor(v, m, 64));
  return v;
}
__device__ __forceinline__ float f4get(const float4& v, int e) {
  return e == 0 ? v.x : e == 1 ? v.y : e == 2 ? v.z : v.w;
}

// Per-chunk accumulate (4 elements x 5 branches)
__device__ __forceinline__ void proc_chunk(
    const float4& c1, const float4& c2, const float4& c3, const float4& c4,
    const float4& cs, float t1[5], float t2[5], float Z[5], float S1[5],
    float& Z1, float& Z20) {
  const float K20 = LOG2E / 20.0f;
#pragma unroll
  for (int e = 0; e < 4; ++e) {
    float w0 = f4get(c1, e);
    float w1 = f4get(c2, e);
    float w2 = f4get(c3, e);
    float w3 = f4get(c4, e);
    float wsv = f4get(cs, e);
    float wm = ((w0 + w1) + w2 + w3) * 0.25f;  // mimic — keep this op order
    float w[5] = {w0, w1, w2, w3, wm};
#pragma unroll
    for (int t = 0; t < 5; ++t) {
      t2[t] = fmaxf(t2[t], fminf(t1[t], w[t]));
      t1[t] = fmaxf(t1[t], w[t]);
      float et = fexp2(w[t] * K20);
      Z[t] += et;
      S1[t] = fmaf(et, w[t] - wsv, S1[t]);
    }
    Z1 += fexp2(wsv * LOG2E);
    Z20 += fexp2(wsv * K20);
  }
}

// ONE WAVE per row; 4 chunks of 5 KB via global_load_lds into
// double-buffered wave-private LDS (10 KB/wave, 40 KB/block). This is the
// session's empirically best configuration (R4: dur 185.165, k_rowstats
// 65.7-66.5 µs, VGPR 52, zero spill). Eleven schedule variants (occupancy
// 16-78%, pipeline depth 0-3, reg/LDS staging, persistent waves) all land
// 65-77 µs — the ~65 µs floor is a latency-structure property of this
// 5-stream+gather pattern, not movable at HIP source level.
__global__ __launch_bounds__(256, 4) void k_rowstats(
    const float* __restrict__ o1, const float* __restrict__ o2,
    const float* __restrict__ o3, const float* __restrict__ o4,
    const float* __restrict__ os, const int* __restrict__ tg,
    float* __restrict__ ws, float* __restrict__ out) {
  const int lane = threadIdx.x & 63;
  const int wv = threadIdx.x >> 6;          // 0..3
  const int row = (blockIdx.x << 2) + wv;   // grid = NB/4
  const size_t base = (size_t)row * NC;

  __shared__ float4 lds[4][2][5][64];       // [wave][buf][matrix][lane] 40 KB

  // zero the output accumulator for k_final's atomics (runs strictly before)
  if (blockIdx.x == 0 && threadIdx.x == 0) out[0] = 0.0f;

  // bulk staging issued first
  float4 r1, r2, r3, r4, rs;

#define STAGE(i, b)                                                       \
  do {                                                                    \
    int f_ = lane + ((i) << 6);                                           \
    if (f_ > NF4 - 1) f_ = NF4 - 1; /* clamp: dup load, masked at c3 */   \
    stage16((const float4*)(o1 + base) + f_, &lds[wv][b][0][0]);          \
    stage16((const float4*)(o2 + base) + f_, &lds[wv][b][1][0]);          \
    stage16((const float4*)(o3 + base) + f_, &lds[wv][b][2][0]);          \
    stage16((const float4*)(o4 + base) + f_, &lds[wv][b][3][0]);          \
    stage16((const float4*)(os + base) + f_, &lds[wv][b][4][0]);          \
  } while (0)

  STAGE(0, 0);
  STAGE(1, 1);

  // target gathers (consumed only at the very end by lane 63)
  const int target = tg[row];
  const float g1 = o1[base + target];
  const float g2 = o2[base + target];
  const float g3 = o3[base + target];
  const float g4 = o4[base + target];
  const float gs = os[base + target];

  float t1[5], t2[5], Z[5], S1[5];
#pragma unroll
  for (int t = 0; t < 5; ++t) {
    t1[t] = -INFINITY; t2[t] = -INFINITY; Z[t] = 0.f; S1[t] = 0.f;
  }
  float Z1 = 0.f, Z20 = 0.f;

#define READC(b)                                                          \
  r1 = lds[wv][b][0][lane]; r2 = lds[wv][b][1][lane];                     \
  r3 = lds[wv][b][2][lane]; r4 = lds[wv][b][3][lane];                     \
  rs = lds[wv][b][4][lane];

  // ---- chunk 0 (buf 0); refill buf 0 with chunk 2 while computing ----
  VMWAIT(5);
  READC(0);
  LGKM0;               // chunk-0 data in VGPRs -> buf 0 free to overwrite
  STAGE(2, 0);
  proc_chunk(r1, r2, r3, r4, rs, t1, t2, Z, S1, Z1, Z20);

  // ---- chunk 1 (buf 1); refill buf 1 with chunk 3 ----
  VMWAIT(5);
  READC(1);
  LGKM0;
  STAGE(3, 1);
  proc_chunk(r1, r2, r3, r4, rs, t1, t2, Z, S1, Z1, Z20);

  // ---- chunk 2 (buf 0) ----
  VMWAIT(5);
  READC(0);
  LGKM0;
  proc_chunk(r1, r2, r3, r4, rs, t1, t2, Z, S1, Z1, Z20);

  // ---- chunk 3 (buf 1): f = lane+192, valid only for lane < 58 ----
  VMWAIT(0);
  READC(1);
  LGKM0;
  if (lane < 58)
    proc_chunk(r1, r2, r3, r4, rs, t1, t2, Z, S1, Z1, Z20);

  // wave-level reductions on the VALU pipe (result in lane 63)
#pragma unroll
  for (int t = 0; t < 5; ++t) dppredtop2(t1[t], t2[t]);
#pragma unroll
  for (int t = 0; t < 5; ++t) { Z[t] = dppredsum(Z[t]); S1[t] = dppredsum(S1[t]); }
  Z1 = dppredsum(Z1);
  Z20 = dppredsum(Z20);

  if (lane == 63) {
    const float gm = ((g1 + g2) + g3 + g4) * 0.25f;  // same op order as wm
    float gg[5] = {g1, g2, g3, g4, gm};

    const float lse_s = flog2(Z20) * LN2;     // logsumexp(out_s/20), unshifted
    const float CE = flog2(Z1) * LN2 - gs;    // -log_softmax(out_s)[target]

#pragma unroll
    for (int t = 0; t < 5; ++t) {
      float lse_t = flog2(Z[t]) * LN2;
      float KD = 400.0f * (S1[t] / (20.0f * Z[t]) - lse_t + lse_s);
      float margin = (t1[t] == gg[t]) ? (t1[t] - t2[t]) : 0.0f;
      ws[(size_t)t * NB + row] = margin;
      ws[(size_t)(5 + t) * NB + row] = gg[t];
      ws[(size_t)(10 + t) * NB + row] = KD;
    }
    ws[(size_t)15 * NB + row] = CE;
    ws[(size_t)16 * NB + row] = fminf(fminf(g1, g2), fminf(g3, g4));
    ws[(size_t)17 * NB + row] = fmaxf(fmaxf(t1[0], t1[1]), fmaxf(t1[2], t1[3]));
  }
#undef STAGE
#undef READC
}

// Fused minmax + loss: every block REDUNDANTLY scans the 64 KB min/max
// columns (L2/L3-resident after k_rowstats -> ~free). Fully unrolled scan so
// all 16 loads are in flight. 32 blocks x 256 (the 128x64 variant measured
// ~2 µs slower in three consecutive rounds).
__global__ __launch_bounds__(256) void k_final(const float* __restrict__ ws,
                                               float* __restrict__ out) {
  const int tid = threadIdx.x;
  const int lane = tid & 63, wv = tid >> 6;
  __shared__ float sMn[4], sMx[4], sA[4];

  float mn = INFINITY, mx = -INFINITY;
  const float4* mnp = (const float4*)(ws + (size_t)16 * NB);
  const float4* mxp = (const float4*)(ws + (size_t)17 * NB);
#pragma unroll
  for (int k = 0; k < 8; ++k) {
    int r4 = tid + (k << 8);                // 8 x 256 = 2048 = NB/4
    float4 a = mnp[r4];
    float4 b = mxp[r4];
    mn = fminf(mn, fminf(fminf(a.x, a.y), fminf(a.z, a.w)));
    mx = fmaxf(mx, fmaxf(fmaxf(b.x, b.y), fmaxf(b.z, b.w)));
  }
  mn = wredmin(mn);
  mx = wredmax(mx);
  if (lane == 0) { sMn[wv] = mn; sMx[wv] = mx; }
  __syncthreads();
  const float a = fminf(fminf(sMn[0], sMn[1]), fminf(sMn[2], sMn[3]));
  const float b = fmaxf(fmaxf(sMx[0], sMx[1]), fmaxf(sMx[2], sMx[3]));
  const float shift = (a < 0.0f) ? (-a + 1e-5f) : 0.0f;
  const float maxp = b + shift;

  const int r = blockIdx.x * 256 + tid;   // 32 blocks x 256 = 8192 rows
  const float K6 = LOG2E / 6.0f;

  float m[5], e[5];
#pragma unroll
  for (int t = 0; t < 5; ++t) m[t] = ws[(size_t)t * NB + r];
  float pm = fmaxf(fmaxf(fmaxf(m[0], m[1]), fmaxf(m[2], m[3])), m[4]);
  float Zl = 0.0f;
#pragma unroll
  for (int t = 0; t < 5; ++t) { e[t] = fexp2((m[t] - pm) * K6); Zl += e[t]; }
  float ce = ws[(size_t)15 * NB + r];
  float rl = 0.0f;
#pragma unroll
  for (int t = 0; t < 5; ++t) {
    float g = ws[(size_t)(5 + t) * NB + r];
    float kd = ws[(size_t)(10 + t) * NB + r];
    float w2 = (g + shift) / maxp;
    float loss = (1.0f - w2) * ce + w2 * kd;
    rl += e[t] * loss;
  }
  float acc = rl / Zl;

  acc = wredsum(acc);
  if (lane == 0) sA[wv] = acc;
  __syncthreads();
  if (tid == 0) {
    float tot = (sA[0] + sA[1]) + (sA[2] + sA[3]);
    atomicAdd(out, tot * (1.0f / 8192.0f));
  }
}

extern "C" void kernel_launch(void* const* d_in, const int* in_sizes, int n_in,
                              void* d_out, int out_size, void* d_ws, size_t ws_size,
                              hipStream_t stream) {
  const float* o1 = (const float*)d_in[0];
  const float* o2 = (const float*)d_in[1];
  const float* o3 = (const float*)d_in[2];
  const float* o4 = (const float*)d_in[3];
  const float* os = (const float*)d_in[4];
  const int* tg = (const int*)d_in[5];
  float* ws = (float*)d_ws;
  float* out = (float*)d_out;

  k_rowstats<<<NB / 4, 256, 0, stream>>>(o1, o2, o3, o4, os, tg, ws, out);
  k_final<<<NB / 256, 256, 0, stream>>>(ws, out);
}